// Round 14
// baseline (649.817 us; speedup 1.0000x reference)
//
#include <hip/hip_runtime.h>

#define FDIM 64
#define NSDIM 64
#define TREP 3
#define EPSV 1e-8f
#define HPART 512   // hyper stage-1 partials
#define HGRP  32    // stage-2a groups (HPART/16)

// ============================================================================
// Register-tile GEMM family: one lane owns one output row. All 16 float4 row
// loads issued up-front into registers (16 VMEM ops in flight -> latency
// amortized); W rows via wave-uniform scalar path. No LDS.
// ============================================================================

__global__ __launch_bounds__(256) void gmat_k(const float* __restrict__ X,
                                              const float* __restrict__ W,
                                              const float* __restrict__ B,
                                              float* __restrict__ G, int nN)
{
  const int t    = blockIdx.y;
  const int lane = threadIdx.x & 63;
  const int wib  = threadIdx.x >> 6;
  const int row  = blockIdx.x * 256 + wib * 64 + lane;
  const float* __restrict__ Wt = W + (size_t)t * FDIM * FDIM;
  const float* __restrict__ Bt = B + t * FDIM;
  float acc[FDIM];
#pragma unroll
  for (int c = 0; c < FDIM; ++c) acc[c] = Bt[c];
  if (row >= nN) return;
  const float4* __restrict__ xr = (const float4*)(X + (size_t)row * FDIM);
  float4 xv[16];
#pragma unroll
  for (int kk = 0; kk < 16; ++kk) xv[kk] = xr[kk];   // 16 loads in flight
  float ss = 0.f;
#pragma unroll
  for (int kk = 0; kk < FDIM / 4; ++kk) {
    const float4 x = xv[kk];
    ss = fmaf(x.x, x.x, fmaf(x.y, x.y, fmaf(x.z, x.z, fmaf(x.w, x.w, ss))));
    const float* __restrict__ w0 = Wt + (kk * 4 + 0) * FDIM;
    const float* __restrict__ w1 = Wt + (kk * 4 + 1) * FDIM;
    const float* __restrict__ w2 = Wt + (kk * 4 + 2) * FDIM;
    const float* __restrict__ w3 = Wt + (kk * 4 + 3) * FDIM;
#pragma unroll
    for (int c = 0; c < FDIM; ++c) acc[c] = fmaf(x.x, w0[c], acc[c]);
#pragma unroll
    for (int c = 0; c < FDIM; ++c) acc[c] = fmaf(x.y, w1[c], acc[c]);
#pragma unroll
    for (int c = 0; c < FDIM; ++c) acc[c] = fmaf(x.z, w2[c], acc[c]);
#pragma unroll
    for (int c = 0; c < FDIM; ++c) acc[c] = fmaf(x.w, w3[c], acc[c]);
  }
  float sq = 0.f;
#pragma unroll
  for (int c = 0; c < FDIM; ++c) sq = fmaf(acc[c], acc[c], sq);
  const float nf = fmaxf(sqrtf(ss), EPSV);
  const float na = fmaxf(sqrtf(sq), EPSV);
  float* __restrict__ grow = G + ((size_t)t * nN + row) * FDIM;
#pragma unroll
  for (int c4 = 0; c4 < FDIM / 4; ++c4) {
    const float4 x = xv[c4];
    ((float4*)grow)[c4] = make_float4(
        fmaf(nf, acc[4 * c4 + 0], -na * x.x),
        fmaf(nf, acc[4 * c4 + 1], -na * x.y),
        fmaf(nf, acc[4 * c4 + 2], -na * x.z),
        fmaf(nf, acc[4 * c4 + 3], -na * x.w));
  }
}

template<bool RELU_IN>
__global__ __launch_bounds__(256) void gemm_k(const float* __restrict__ X,
                                              const float* __restrict__ W,
                                              float* __restrict__ out, int rows,
                                              float* __restrict__ scaled,
                                              const float* __restrict__ dinv, int nScaled)
{
  const int lane = threadIdx.x & 63;
  const int wib  = threadIdx.x >> 6;
  const int row  = blockIdx.x * 256 + wib * 64 + lane;
  if (row >= rows) return;
  const float4* __restrict__ xr = (const float4*)(X + (size_t)row * FDIM);
  float4 xv[16];
#pragma unroll
  for (int kk = 0; kk < 16; ++kk) xv[kk] = xr[kk];   // 16 loads in flight
  float acc[FDIM];
#pragma unroll
  for (int c = 0; c < FDIM; ++c) acc[c] = 0.f;
#pragma unroll
  for (int kk = 0; kk < FDIM / 4; ++kk) {
    float4 x = xv[kk];
    if (RELU_IN) {
      x.x = fmaxf(x.x, 0.f); x.y = fmaxf(x.y, 0.f);
      x.z = fmaxf(x.z, 0.f); x.w = fmaxf(x.w, 0.f);
    }
    const float* __restrict__ w0 = W + (kk * 4 + 0) * FDIM;
    const float* __restrict__ w1 = W + (kk * 4 + 1) * FDIM;
    const float* __restrict__ w2 = W + (kk * 4 + 2) * FDIM;
    const float* __restrict__ w3 = W + (kk * 4 + 3) * FDIM;
#pragma unroll
    for (int c = 0; c < FDIM; ++c) acc[c] = fmaf(x.x, w0[c], acc[c]);
#pragma unroll
    for (int c = 0; c < FDIM; ++c) acc[c] = fmaf(x.y, w1[c], acc[c]);
#pragma unroll
    for (int c = 0; c < FDIM; ++c) acc[c] = fmaf(x.z, w2[c], acc[c]);
#pragma unroll
    for (int c = 0; c < FDIM; ++c) acc[c] = fmaf(x.w, w3[c], acc[c]);
  }
  float* __restrict__ orow = out + (size_t)row * FDIM;
#pragma unroll
  for (int c4 = 0; c4 < FDIM / 4; ++c4)
    ((float4*)orow)[c4] = make_float4(acc[4 * c4], acc[4 * c4 + 1],
                                      acc[4 * c4 + 2], acc[4 * c4 + 3]);
  if (scaled != nullptr && row < nScaled) {
    const float dv = dinv[row];
    float* __restrict__ srow = scaled + (size_t)row * FDIM;
#pragma unroll
    for (int c4 = 0; c4 < FDIM / 4; ++c4)
      ((float4*)srow)[c4] = make_float4(acc[4 * c4] * dv, acc[4 * c4 + 1] * dv,
                                        acc[4 * c4 + 2] * dv, acc[4 * c4 + 3] * dv);
  }
}

__global__ __launch_bounds__(256) void logits_k(const float* __restrict__ X,
                                                const float* __restrict__ W,
                                                const float* __restrict__ B,
                                                float* __restrict__ H,
                                                int rows, int nN)
{
  const int lane = threadIdx.x & 63;
  const int wib  = threadIdx.x >> 6;
  const int row  = blockIdx.x * 256 + wib * 64 + lane;
  if (row >= rows) return;
  const float4* __restrict__ xr = (const float4*)(X + (size_t)row * FDIM);
  float4 xv[16];
#pragma unroll
  for (int kk = 0; kk < 16; ++kk) xv[kk] = xr[kk];
  float acc[NSDIM];
#pragma unroll
  for (int c = 0; c < NSDIM; ++c) acc[c] = B[c];
#pragma unroll
  for (int kk = 0; kk < FDIM / 4; ++kk) {
    float4 x = xv[kk];
    x.x = fmaxf(x.x, 0.f); x.y = fmaxf(x.y, 0.f);
    x.z = fmaxf(x.z, 0.f); x.w = fmaxf(x.w, 0.f);
    const float* __restrict__ w0 = W + (kk * 4 + 0) * NSDIM;
    const float* __restrict__ w1 = W + (kk * 4 + 1) * NSDIM;
    const float* __restrict__ w2 = W + (kk * 4 + 2) * NSDIM;
    const float* __restrict__ w3 = W + (kk * 4 + 3) * NSDIM;
#pragma unroll
    for (int c = 0; c < NSDIM; ++c) acc[c] = fmaf(x.x, w0[c], acc[c]);
#pragma unroll
    for (int c = 0; c < NSDIM; ++c) acc[c] = fmaf(x.y, w1[c], acc[c]);
#pragma unroll
    for (int c = 0; c < NSDIM; ++c) acc[c] = fmaf(x.z, w2[c], acc[c]);
#pragma unroll
    for (int c = 0; c < NSDIM; ++c) acc[c] = fmaf(x.w, w3[c], acc[c]);
  }
  float bv = acc[0]; int bi = 0;
#pragma unroll
  for (int c = 1; c < NSDIM; ++c)
    if (acc[c] > bv) { bv = acc[c]; bi = c; }   // strict > : first-index tiebreak
  int v = row;
  while (v >= nN) v -= nN;
  atomicAdd(&H[(size_t)v * NSDIM + bi], 1.f);
}

__global__ __launch_bounds__(256) void dots_k(const float* __restrict__ X,
                                              const float* __restrict__ WT,
                                              float* __restrict__ out2, int nN)
{
  const int lane = threadIdx.x & 63;
  const int wib  = threadIdx.x >> 6;
  const int row  = blockIdx.x * 256 + wib * 64 + lane;
  if (row >= nN) return;
  const float4* __restrict__ xr = (const float4*)(X + (size_t)row * FDIM);
  float4 xv[16];
#pragma unroll
  for (int kk = 0; kk < 16; ++kk) xv[kk] = xr[kk];
  float acc[NSDIM];
#pragma unroll
  for (int c = 0; c < NSDIM; ++c) acc[c] = 0.f;
#pragma unroll
  for (int kk = 0; kk < FDIM / 4; ++kk) {
    const float4 x = xv[kk];
    const float* __restrict__ w0 = WT + (kk * 4 + 0) * NSDIM;
    const float* __restrict__ w1 = WT + (kk * 4 + 1) * NSDIM;
    const float* __restrict__ w2 = WT + (kk * 4 + 2) * NSDIM;
    const float* __restrict__ w3 = WT + (kk * 4 + 3) * NSDIM;
#pragma unroll
    for (int c = 0; c < NSDIM; ++c) acc[c] = fmaf(x.x, w0[c], acc[c]);
#pragma unroll
    for (int c = 0; c < NSDIM; ++c) acc[c] = fmaf(x.y, w1[c], acc[c]);
#pragma unroll
    for (int c = 0; c < NSDIM; ++c) acc[c] = fmaf(x.z, w2[c], acc[c]);
#pragma unroll
    for (int c = 0; c < NSDIM; ++c) acc[c] = fmaf(x.w, w3[c], acc[c]);
  }
#pragma unroll
  for (int c = 0; c < NSDIM; ++c) acc[c] *= 0.125f;
#pragma unroll
  for (int b = 0; b < 4; ++b) {
    float* __restrict__ orow = out2 + ((size_t)b * nN + row) * NSDIM;
#pragma unroll
    for (int c4 = 0; c4 < NSDIM / 4; ++c4)
      ((float4*)orow)[c4] = make_float4(acc[4 * c4], acc[4 * c4 + 1],
                                        acc[4 * c4 + 2], acc[4 * c4 + 3]);
  }
}

// ============================================================================
// Bucket-staged CSR build (atomic-light, write-clean)
// ============================================================================

__global__ __launch_bounds__(256) void bkhist2_k(const int* __restrict__ src,
                                                 const int* __restrict__ dst,
                                                 int* __restrict__ bkcntS,
                                                 int* __restrict__ bkcntD, int nE)
{
  __shared__ int hs[256], hd[256];
  const int tid = threadIdx.x;
  hs[tid] = 0; hd[tid] = 0;
  __syncthreads();
  for (int e = blockIdx.x * 256 + tid; e < nE; e += gridDim.x * 256) {
    atomicAdd(&hs[src[e] >> 8], 1);
    atomicAdd(&hd[dst[e] >> 8], 1);
  }
  __syncthreads();
  if (hs[tid]) atomicAdd(&bkcntS[tid], hs[tid]);
  if (hd[tid]) atomicAdd(&bkcntD[tid], hd[tid]);
}

__global__ __launch_bounds__(256) void bkscan2_k(const int* __restrict__ cS,
                                                 const int* __restrict__ cD,
                                                 int* __restrict__ offS, int* __restrict__ curS,
                                                 int* __restrict__ offD, int* __restrict__ curD,
                                                 int NB)
{
  __shared__ int s[256];
  const int tid = threadIdx.x;
  int v = (tid < NB) ? cS[tid] : 0;
  s[tid] = v; __syncthreads();
#pragma unroll
  for (int o = 1; o < 256; o <<= 1) {
    const int t = (tid >= o) ? s[tid - o] : 0;
    __syncthreads(); s[tid] += t; __syncthreads();
  }
  if (tid < NB) { offS[tid] = s[tid] - v; curS[tid] = s[tid] - v; }
  if (tid == 255) offS[NB] = s[255];
  __syncthreads();
  v = (tid < NB) ? cD[tid] : 0;
  s[tid] = v; __syncthreads();
#pragma unroll
  for (int o = 1; o < 256; o <<= 1) {
    const int t = (tid >= o) ? s[tid - o] : 0;
    __syncthreads(); s[tid] += t; __syncthreads();
  }
  if (tid < NB) { offD[tid] = s[tid] - v; curD[tid] = s[tid] - v; }
  if (tid == 255) offD[NB] = s[255];
}

__global__ __launch_bounds__(256) void bkfillS_k(const int* __restrict__ src,
                                                 const int* __restrict__ dst,
                                                 int* __restrict__ bkcur,
                                                 uint2* __restrict__ ebuf, int nE)
{
  __shared__ int hist[256], gbase[256];
  const int tid = threadIdx.x;
  for (int cb = blockIdx.x * 2048; cb < nE; cb += gridDim.x * 2048) {
    hist[tid] = 0;
    __syncthreads();
    int bk[8], ofs[8], sv[8], dv[8];
#pragma unroll
    for (int k = 0; k < 8; ++k) {
      const int i = cb + k * 256 + tid;
      bk[k] = -1;
      if (i < nE) {
        sv[k] = src[i];
        dv[k] = dst[i];
        bk[k] = sv[k] >> 8;
        ofs[k] = atomicAdd(&hist[bk[k]], 1);
      }
    }
    __syncthreads();
    if (hist[tid] > 0) gbase[tid] = atomicAdd(&bkcur[tid], hist[tid]);
    __syncthreads();
#pragma unroll
    for (int k = 0; k < 8; ++k)
      if (bk[k] >= 0)
        ebuf[gbase[bk[k]] + ofs[k]] = make_uint2((unsigned)sv[k], (unsigned)dv[k]);
    __syncthreads();
  }
}

__global__ __launch_bounds__(256) void cntfillS_k(const uint2* __restrict__ ebuf,
                                                  const int* __restrict__ bkoff,
                                                  int* __restrict__ cnt, int nN)
{
  __shared__ int h[256];
  const int tid = threadIdx.x, b = blockIdx.x;
  h[tid] = 0; __syncthreads();
  const int lo = bkoff[b], hi = bkoff[b + 1];
  for (int i = lo + tid; i < hi; i += 256)
    atomicAdd(&h[ebuf[i].x & 255u], 1);
  __syncthreads();
  const int node = b * 256 + tid;
  if (node < nN) cnt[node] = h[tid];
}

__global__ __launch_bounds__(256) void scanA_k(const int* __restrict__ cnt,
                                               int* __restrict__ rowoff,
                                               int* __restrict__ tilesum, int nTot)
{
  __shared__ int s[256];
  const int i = blockIdx.x * 256 + threadIdx.x;
  const int v = (i < nTot) ? cnt[i] : 0;
  s[threadIdx.x] = v;
  __syncthreads();
#pragma unroll
  for (int o = 1; o < 256; o <<= 1) {
    const int t = (threadIdx.x >= o) ? s[threadIdx.x - o] : 0;
    __syncthreads();
    s[threadIdx.x] += t;
    __syncthreads();
  }
  if (i < nTot) rowoff[i] = s[threadIdx.x] - v;
  if (threadIdx.x == 255) tilesum[blockIdx.x] = s[255];
}

__global__ __launch_bounds__(256) void scanB_k(const int* __restrict__ tilesum,
                                               int* __restrict__ tileoff, int ntiles)
{
  __shared__ int s[256];
  __shared__ int carry;
  if (threadIdx.x == 0) carry = 0;
  __syncthreads();
  for (int base = 0; base < ntiles; base += 256) {
    const int idx = base + threadIdx.x;
    const int v = (idx < ntiles) ? tilesum[idx] : 0;
    s[threadIdx.x] = v;
    __syncthreads();
#pragma unroll
    for (int o = 1; o < 256; o <<= 1) {
      const int t = (threadIdx.x >= o) ? s[threadIdx.x - o] : 0;
      __syncthreads();
      s[threadIdx.x] += t;
      __syncthreads();
    }
    if (idx < ntiles) tileoff[idx] = carry + s[threadIdx.x] - v;
    __syncthreads();
    if (threadIdx.x == 0) carry += s[255];
    __syncthreads();
  }
  if (threadIdx.x == 0) tileoff[ntiles] = carry;
}

__global__ __launch_bounds__(256) void scanC_k(int* __restrict__ rowoff,
                                               int* __restrict__ cursor,
                                               const int* __restrict__ tileoff,
                                               int nTot, int ntiles)
{
  const int i = blockIdx.x * 256 + threadIdx.x;
  if (i < nTot) {
    const int v = rowoff[i] + tileoff[i >> 8];
    rowoff[i] = v;
    cursor[i] = v;
  }
  if (i == 0) rowoff[nTot] = tileoff[ntiles];
}

__global__ __launch_bounds__(256) void csrfill_k(const uint2* __restrict__ ebuf,
                                                 const int* __restrict__ bkoff,
                                                 const int* __restrict__ rowoff,
                                                 unsigned* __restrict__ out, int nN)
{
  __shared__ int cur[256];
  const int tid = threadIdx.x, b = blockIdx.x;
  const int node = b * 256 + tid;
  cur[tid] = (node < nN) ? rowoff[node] : 0;
  __syncthreads();
  const int lo = bkoff[b], hi = bkoff[b + 1];
  for (int i = lo + tid; i < hi; i += 256) {
    const uint2 p = ebuf[i];
    const int pos = atomicAdd(&cur[(int)(p.x & 255u)], 1);
    out[pos] = p.y;
  }
}

// ---------- mask (no atomics): group-per-source, 2 edges in flight ----------
__global__ void mask_k(const int* __restrict__ rowoffS, unsigned* __restrict__ slots,
                       const float* __restrict__ G, const float* __restrict__ f, int nN)
{
  const int lane  = threadIdx.x & 63;
  const int glane = lane & 15;
  const int grp   = lane >> 4;
  const int wib   = threadIdx.x >> 6;
  const int wpb   = blockDim.x >> 6;
  const float4* __restrict__ G4 = (const float4*)G;
  const float4* __restrict__ f4 = (const float4*)f;
  const int nwave = gridDim.x * wpb;
  for (int sbase = (blockIdx.x * wpb + wib) * 4; sbase < nN; sbase += nwave * 4) {
    const int s = sbase + grp;
    const bool sv = s < nN;
    const int ss = sv ? s : 0;
    const int start = rowoffS[ss];
    const int end   = sv ? rowoffS[ss + 1] : start;
    const float4 g0 = G4[((size_t)0 * nN + ss) * 16 + glane];
    const float4 g1 = G4[((size_t)1 * nN + ss) * 16 + glane];
    const float4 g2 = G4[((size_t)2 * nN + ss) * 16 + glane];
    int base = start;
    for (; base + 2 <= end; base += 2) {
      const unsigned w0 = slots[base + 0] & 0xFFFFFu;
      const unsigned w1 = slots[base + 1] & 0xFFFFFu;
      const float4 fv0 = f4[(size_t)w0 * 16 + glane];
      const float4 fv1 = f4[(size_t)w1 * 16 + glane];
      float p00 = fmaf(fv0.x, g0.x, fmaf(fv0.y, g0.y, fmaf(fv0.z, g0.z, fv0.w * g0.w)));
      float p01 = fmaf(fv0.x, g1.x, fmaf(fv0.y, g1.y, fmaf(fv0.z, g1.z, fv0.w * g1.w)));
      float p02 = fmaf(fv0.x, g2.x, fmaf(fv0.y, g2.y, fmaf(fv0.z, g2.z, fv0.w * g2.w)));
      float p10 = fmaf(fv1.x, g0.x, fmaf(fv1.y, g0.y, fmaf(fv1.z, g0.z, fv1.w * g0.w)));
      float p11 = fmaf(fv1.x, g1.x, fmaf(fv1.y, g1.y, fmaf(fv1.z, g1.z, fv1.w * g1.w)));
      float p12 = fmaf(fv1.x, g2.x, fmaf(fv1.y, g2.y, fmaf(fv1.z, g2.z, fv1.w * g2.w)));
#pragma unroll
      for (int o = 8; o > 0; o >>= 1) {
        p00 += __shfl_xor(p00, o); p01 += __shfl_xor(p01, o); p02 += __shfl_xor(p02, o);
        p10 += __shfl_xor(p10, o); p11 += __shfl_xor(p11, o); p12 += __shfl_xor(p12, o);
      }
      if (glane == 0) {
        const unsigned m0 = (p00 > 0.f ? 1u : 0u) | (p01 > 0.f ? 2u : 0u) | (p02 > 0.f ? 4u : 0u);
        const unsigned m1 = (p10 > 0.f ? 1u : 0u) | (p11 > 0.f ? 2u : 0u) | (p12 > 0.f ? 4u : 0u);
        if (m0) slots[base + 0] = w0 | (m0 << 20);
        if (m1) slots[base + 1] = w1 | (m1 << 20);
      }
    }
    if (base < end) {
      const unsigned d = slots[base] & 0xFFFFFu;
      const float4 fv = f4[(size_t)d * 16 + glane];
      float p0 = fmaf(fv.x, g0.x, fmaf(fv.y, g0.y, fmaf(fv.z, g0.z, fv.w * g0.w)));
      float p1 = fmaf(fv.x, g1.x, fmaf(fv.y, g1.y, fmaf(fv.z, g1.z, fv.w * g1.w)));
      float p2 = fmaf(fv.x, g2.x, fmaf(fv.y, g2.y, fmaf(fv.z, g2.z, fv.w * g2.w)));
#pragma unroll
      for (int o = 8; o > 0; o >>= 1) {
        p0 += __shfl_xor(p0, o);
        p1 += __shfl_xor(p1, o);
        p2 += __shfl_xor(p2, o);
      }
      if (glane == 0) {
        unsigned m = (p0 > 0.f ? 1u : 0u) | (p1 > 0.f ? 2u : 0u) | (p2 > 0.f ? 4u : 0u);
        if (m) slots[base] = d | (m << 20);
      }
    }
  }
}

__global__ __launch_bounds__(256) void bkfillD_k(const int* __restrict__ rowoffS,
                                                 const unsigned* __restrict__ slots,
                                                 int* __restrict__ bkcur,
                                                 uint2* __restrict__ ebuf, int nN)
{
  __shared__ int roff[257];
  __shared__ int hist[256], gbase[256];
  const int tid = threadIdx.x;
  const int sb  = blockIdx.x;
  const int nb0 = sb * 256;
  {
    int idx = nb0 + tid; if (idx > nN) idx = nN;
    roff[tid] = rowoffS[idx];
    if (tid == 0) { int e = nb0 + 256; if (e > nN) e = nN; roff[256] = rowoffS[e]; }
  }
  __syncthreads();
  const int estart = roff[0], eend = roff[256];
  for (int cb = estart; cb < eend; cb += 2048) {
    hist[tid] = 0;
    __syncthreads();
    int bk[8], ofs[8]; unsigned dv[8], pv[8];
#pragma unroll
    for (int k = 0; k < 8; ++k) {
      const int i = cb + k * 256 + tid;
      bk[k] = -1;
      if (i < eend) {
        const unsigned v = slots[i];
        const unsigned d = v & 0xFFFFFu;
        int lo = 0, hi = 256;
#pragma unroll
        for (int st = 0; st < 8; ++st) {
          const int mid = (lo + hi) >> 1;
          if (roff[mid] <= i) lo = mid; else hi = mid;
        }
        dv[k] = d;
        pv[k] = (unsigned)(nb0 + lo) | (v & 0xFFF00000u);
        bk[k] = (int)(d >> 8);
        ofs[k] = atomicAdd(&hist[bk[k]], 1);
      }
    }
    __syncthreads();
    if (hist[tid] > 0) gbase[tid] = atomicAdd(&bkcur[tid], hist[tid]);
    __syncthreads();
#pragma unroll
    for (int k = 0; k < 8; ++k)
      if (bk[k] >= 0) ebuf[gbase[bk[k]] + ofs[k]] = make_uint2(dv[k], pv[k]);
    __syncthreads();
  }
}

__global__ __launch_bounds__(256) void cntfillD_k(const uint2* __restrict__ ebuf,
                                                  const int* __restrict__ bkoff,
                                                  int* __restrict__ cntD,
                                                  int* __restrict__ cntR, int nN)
{
  __shared__ int h0[256], h1[256], h2[256], h3[256];
  const int tid = threadIdx.x, b = blockIdx.x;
  h0[tid] = 0; h1[tid] = 0; h2[tid] = 0; h3[tid] = 0;
  __syncthreads();
  const int lo = bkoff[b], hi = bkoff[b + 1];
  for (int i = lo + tid; i < hi; i += 256) {
    const uint2 p = ebuf[i];
    const int l = (int)(p.x & 255u);
    const unsigned m = p.y >> 20;
    atomicAdd(&h0[l], 1);
    if (m & 1u) atomicAdd(&h1[l], 1);
    if (m & 2u) atomicAdd(&h2[l], 1);
    if (m & 4u) atomicAdd(&h3[l], 1);
  }
  __syncthreads();
  const int node = b * 256 + tid;
  if (node < nN) {
    cntD[node] = h0[tid];
    cntR[node] = h1[tid];
    cntR[nN + node] = h2[tid];
    cntR[2 * nN + node] = h3[tid];
  }
}

__global__ void dinv_k(const int* __restrict__ cntD0, const int* __restrict__ cntR,
                       float* __restrict__ dinv, int nN)
{
  int i = blockIdx.x * blockDim.x + threadIdx.x;
  int tot = 4 * nN;
  if (i < tot) {
    float deg = (i < nN) ? ((float)cntD0[i] + 1.f) : ((float)cntR[i - nN] + 2.f);
    dinv[i] = 1.f / sqrtf(deg);
  }
}

// ---------- fused CSR gather + GCN finish (group-per-destination, float4 path) ----------
template<bool L0, bool RELU>
__global__ void gather_finish_k(const int* __restrict__ rowoff, const unsigned* __restrict__ csr,
                                const float* __restrict__ xws, const float* __restrict__ xw,
                                const float* __restrict__ dinv, const float* __restrict__ bias,
                                float* __restrict__ out, int nN)
{
  const int lane  = threadIdx.x & 63;
  const int glane = lane & 15;
  const int grp   = lane >> 4;
  const int wib   = threadIdx.x >> 6;
  const int wpb   = blockDim.x >> 6;
  const float4* __restrict__ xws4 = (const float4*)xws;
  const float4* __restrict__ xw4  = (const float4*)xw;
  float4* __restrict__ out4 = (float4*)out;
  const float4 b4 = ((const float4*)bias)[glane];
  const int nwave = gridDim.x * wpb;
  for (int dbase = (blockIdx.x * wpb + wib) * 4; dbase < nN; dbase += nwave * 4) {
    const int d = dbase + grp;
    const bool dv = d < nN;
    const int dd = dv ? d : 0;
    const int start = rowoff[dd];
    const int end   = dv ? rowoff[dd + 1] : start;
    float4 A0 = make_float4(0.f, 0.f, 0.f, 0.f);
    float4 A1 = A0, A2 = A0, A3 = A0;
    int j = start;
    for (; j + 4 <= end; j += 4) {
      const unsigned c0 = csr[j + 0], c1 = csr[j + 1], c2 = csr[j + 2], c3 = csr[j + 3];
      const float4 v0 = xws4[(size_t)(c0 & 0xFFFFFu) * 16 + glane];
      const float4 v1 = xws4[(size_t)(c1 & 0xFFFFFu) * 16 + glane];
      const float4 v2 = xws4[(size_t)(c2 & 0xFFFFFu) * 16 + glane];
      const float4 v3 = xws4[(size_t)(c3 & 0xFFFFFu) * 16 + glane];
      A0.x += v0.x; A0.y += v0.y; A0.z += v0.z; A0.w += v0.w;
      if (c0 & 0x100000u) { A1.x += v0.x; A1.y += v0.y; A1.z += v0.z; A1.w += v0.w; }
      if (c0 & 0x200000u) { A2.x += v0.x; A2.y += v0.y; A2.z += v0.z; A2.w += v0.w; }
      if (c0 & 0x400000u) { A3.x += v0.x; A3.y += v0.y; A3.z += v0.z; A3.w += v0.w; }
      A0.x += v1.x; A0.y += v1.y; A0.z += v1.z; A0.w += v1.w;
      if (c1 & 0x100000u) { A1.x += v1.x; A1.y += v1.y; A1.z += v1.z; A1.w += v1.w; }
      if (c1 & 0x200000u) { A2.x += v1.x; A2.y += v1.y; A2.z += v1.z; A2.w += v1.w; }
      if (c1 & 0x400000u) { A3.x += v1.x; A3.y += v1.y; A3.z += v1.z; A3.w += v1.w; }
      A0.x += v2.x; A0.y += v2.y; A0.z += v2.z; A0.w += v2.w;
      if (c2 & 0x100000u) { A1.x += v2.x; A1.y += v2.y; A1.z += v2.z; A1.w += v2.w; }
      if (c2 & 0x200000u) { A2.x += v2.x; A2.y += v2.y; A2.z += v2.z; A2.w += v2.w; }
      if (c2 & 0x400000u) { A3.x += v2.x; A3.y += v2.y; A3.z += v2.z; A3.w += v2.w; }
      A0.x += v3.x; A0.y += v3.y; A0.z += v3.z; A0.w += v3.w;
      if (c3 & 0x100000u) { A1.x += v3.x; A1.y += v3.y; A1.z += v3.z; A1.w += v3.w; }
      if (c3 & 0x200000u) { A2.x += v3.x; A2.y += v3.y; A2.z += v3.z; A2.w += v3.w; }
      if (c3 & 0x400000u) { A3.x += v3.x; A3.y += v3.y; A3.z += v3.z; A3.w += v3.w; }
    }
    for (; j < end; ++j) {
      const unsigned c0 = csr[j];
      const float4 v0 = xws4[(size_t)(c0 & 0xFFFFFu) * 16 + glane];
      A0.x += v0.x; A0.y += v0.y; A0.z += v0.z; A0.w += v0.w;
      if (c0 & 0x100000u) { A1.x += v0.x; A1.y += v0.y; A1.z += v0.z; A1.w += v0.w; }
      if (c0 & 0x200000u) { A2.x += v0.x; A2.y += v0.y; A2.z += v0.z; A2.w += v0.w; }
      if (c0 & 0x400000u) { A3.x += v0.x; A3.y += v0.y; A3.z += v0.z; A3.w += v0.w; }
    }
    if (!dv) continue;
    const float di0 = dinv[d];
    const float4 xs  = xws4[(size_t)d * 16 + glane];
    const float4 xb0 = xw4[(size_t)d * 16 + glane];

    float4 r0;
    r0.x = fmaf(A0.x + xs.x, di0, b4.x);
    r0.y = fmaf(A0.y + xs.y, di0, b4.y);
    r0.z = fmaf(A0.z + xs.z, di0, b4.z);
    r0.w = fmaf(A0.w + xs.w, di0, b4.w);
    if (RELU) {
      r0.x = fmaxf(r0.x, 0.f); r0.y = fmaxf(r0.y, 0.f);
      r0.z = fmaxf(r0.z, 0.f); r0.w = fmaxf(r0.w, 0.f);
    }
    out4[(size_t)d * 16 + glane] = r0;

#pragma unroll
    for (int t = 1; t <= 3; ++t) {
      const float4 At = (t == 1) ? A1 : (t == 2) ? A2 : A3;
      const float dit = dinv[t * nN + d];
      const float4 self = L0 ? xb0 : xw4[((size_t)t * nN + d) * 16 + glane];
      float4 r;
      r.x = fmaf(At.x + xs.x + self.x * dit, dit, b4.x);
      r.y = fmaf(At.y + xs.y + self.y * dit, dit, b4.y);
      r.z = fmaf(At.z + xs.z + self.z * dit, dit, b4.z);
      r.w = fmaf(At.w + xs.w + self.w * dit, dit, b4.w);
      if (RELU) {
        r.x = fmaxf(r.x, 0.f); r.y = fmaxf(r.y, 0.f);
        r.z = fmaxf(r.z, 0.f); r.w = fmaxf(r.w, 0.f);
      }
      out4[((size_t)t * nN + d) * 16 + glane] = r;
    }
  }
}

// ---------- hyper stage 1: per-block LDS accumulate -> private partial ----------
__global__ __launch_bounds__(256) void hyper1_k(const float* __restrict__ H,
                                                const float* __restrict__ x2,
                                                float* __restrict__ partial, int nN)
{
  __shared__ float hl[NSDIM * FDIM];
  for (int i = threadIdx.x; i < NSDIM * FDIM; i += blockDim.x) hl[i] = 0.f;
  __syncthreads();
  const int lane = threadIdx.x & 63;
  const int wib  = threadIdx.x >> 6;
  const int wpb  = blockDim.x >> 6;
  for (int i = blockIdx.x * wpb + wib; i < nN; i += gridDim.x * wpb) {
    float hv = H[(size_t)i * NSDIM + lane];
    unsigned long long ball = __ballot(hv > 0.f);
    float x = x2[(size_t)i * FDIM + lane];
    while (ball) {
      int j = __ffsll((unsigned long long)ball) - 1;
      ball &= ball - 1;
      atomicAdd(&hl[j * FDIM + lane], x);
    }
  }
  __syncthreads();
  float* __restrict__ po = partial + (size_t)blockIdx.x * NSDIM * FDIM;
  for (int i = threadIdx.x; i < NSDIM * FDIM; i += blockDim.x)
    po[i] = hl[i];
}

// ---------- hyper stage 2a ----------
__global__ __launch_bounds__(256) void hyper2a_k(const float* __restrict__ partial,
                                                 float* __restrict__ part2)
{
  const int idx = blockIdx.x * 256 + threadIdx.x;   // [0,4096)
  const int g   = blockIdx.y;                       // [0,HGRP)
  const float* __restrict__ p = partial + ((size_t)g * 16) * (NSDIM * FDIM) + idx;
  float s0 = 0.f, s1 = 0.f, s2 = 0.f, s3 = 0.f;
#pragma unroll
  for (int k = 0; k < 16; k += 4) {
    s0 += p[(size_t)(k + 0) * NSDIM * FDIM];
    s1 += p[(size_t)(k + 1) * NSDIM * FDIM];
    s2 += p[(size_t)(k + 2) * NSDIM * FDIM];
    s3 += p[(size_t)(k + 3) * NSDIM * FDIM];
  }
  part2[(size_t)g * NSDIM * FDIM + idx] = (s0 + s1) + (s2 + s3);
}

// ---------- hyper stage 2b ----------
__global__ __launch_bounds__(256) void hyper2b_k(const float* __restrict__ part2,
                                                 float* __restrict__ out1,
                                                 float* __restrict__ hyperT)
{
  const int idx = blockIdx.x * 256 + threadIdx.x;   // [0,4096)
  const float* __restrict__ p = part2 + idx;
  float s0 = 0.f, s1 = 0.f, s2 = 0.f, s3 = 0.f;
#pragma unroll
  for (int g = 0; g < HGRP; g += 4) {
    s0 += p[(size_t)(g + 0) * NSDIM * FDIM];
    s1 += p[(size_t)(g + 1) * NSDIM * FDIM];
    s2 += p[(size_t)(g + 2) * NSDIM * FDIM];
    s3 += p[(size_t)(g + 3) * NSDIM * FDIM];
  }
  const float s = (s0 + s1) + (s2 + s3);
  out1[idx] = s;
  const int j = idx >> 6, k = idx & 63;
  hyperT[k * NSDIM + j] = s;
}

__global__ void colhist_k(const float* __restrict__ H, int* __restrict__ hist, int nN)
{
  const int lane = threadIdx.x & 63;
  const int wid  = blockIdx.x * (blockDim.x >> 6) + (threadIdx.x >> 6);
  const int nw   = gridDim.x * (blockDim.x >> 6);
  int c0 = 0, c1 = 0, c2 = 0, c3 = 0, c4 = 0;
  for (int i = wid; i < nN; i += nw) {
    const int v = (int)H[(size_t)i * NSDIM + lane];
    c0 += (v == 0); c1 += (v == 1); c2 += (v == 2); c3 += (v == 3); c4 += (v == 4);
  }
  if (c0) atomicAdd(&hist[0 * NSDIM + lane], c0);
  if (c1) atomicAdd(&hist[1 * NSDIM + lane], c1);
  if (c2) atomicAdd(&hist[2 * NSDIM + lane], c2);
  if (c3) atomicAdd(&hist[3 * NSDIM + lane], c3);
  if (c4) atomicAdd(&hist[4 * NSDIM + lane], c4);
}

__global__ void colfin_k(const int* __restrict__ hist, float* __restrict__ cmax,
                         float* __restrict__ cden)
{
  const int j = threadIdx.x;
  if (j < NSDIM) {
    const int s0 = hist[j], s1 = hist[NSDIM + j], s2 = hist[2 * NSDIM + j];
    const int s3 = hist[3 * NSDIM + j], s4 = hist[4 * NSDIM + j];
    int m = 0;
    if (s1 > 0) m = 1;
    if (s2 > 0) m = 2;
    if (s3 > 0) m = 3;
    if (s4 > 0) m = 4;
    float den = 0.f;
    den += (float)s0 * expf((float)(0 - m));
    den += (float)s1 * expf((float)(1 - m));
    den += (float)s2 * expf((float)(2 - m));
    den += (float)s3 * expf((float)(3 - m));
    den += (float)s4 * expf((float)(4 - m));
    cmax[j] = (float)m;
    cden[j] = den;
  }
}

__global__ void hsoft_k(const float* __restrict__ H, const float* __restrict__ cmax,
                        const float* __restrict__ cden, float* __restrict__ out0, int nN)
{
  int idx = blockIdx.x * blockDim.x + threadIdx.x;
  int tot = nN * NSDIM;
  if (idx < tot) {
    int j = idx & (NSDIM - 1);
    out0[idx] = expf(H[idx] - cmax[j]) / cden[j];
  }
}

// ---------- host ----------
extern "C" void kernel_launch(void* const* d_in, const int* in_sizes, int n_in,
                              void* d_out, int out_size, void* d_ws, size_t ws_size,
                              hipStream_t stream)
{
  const int* edge_index = (const int*)d_in[0];
  const float* features = (const float*)d_in[1];
  const float* W_lin    = (const float*)d_in[2];
  const float* b_lin    = (const float*)d_in[3];
  const float* gcn0_W   = (const float*)d_in[4];
  const float* gcn0_b   = (const float*)d_in[5];
  const float* gcn1_W   = (const float*)d_in[6];
  const float* gcn1_b   = (const float*)d_in[7];
  const float* lin1_W   = (const float*)d_in[8];
  const float* lin1_b   = (const float*)d_in[9];

  const int E = in_sizes[0] / 2;
  const int N = in_sizes[1] / FDIM;

  const int* src = edge_index;
  const int* dst = edge_index + E;

  const int NB = (N + 255) >> 8;

  // workspace layout
  float* ws = (float*)d_ws;
  float* G  = ws;                                      // 3NF; aliased by ebuf + xws
  uint2* ebuf = (uint2*)G;                             // E pairs (8B) - G dead at use
  float* xws  = G;                                     // N*F scaled table (after csrD)

  int* ip = (int*)(G + (size_t)TREP * N * FDIM);
  int* bkcntS = ip; ip += 256;
  int* bkcntD = ip; ip += 256;
  int* bkoffS = ip; ip += 264;
  int* bkcurS = ip; ip += 256;
  int* bkoffD = ip; ip += 264;
  int* bkcurD = ip; ip += 256;
  int* cntS   = ip; ip += N;
  int* cntD   = ip; ip += N;
  int* cntR   = ip; ip += 3 * N;
  int* rowoffS = ip; ip += N + 64;
  int* rowoffD = ip; ip += N + 64;
  int* tilesum = ip; ip += (N + 255) / 256 + 8;
  int* tileoff = ip; ip += (N + 255) / 256 + 8;
  int* hist5   = ip; ip += 5 * NSDIM;
  float* dinv = (float*)ip; ip += 4 * N;
  unsigned* slots = (unsigned*)ip; ip += 2 * E;        // src CSR [0,E) | dst CSR [E,2E)
  float* xw0  = (float*)ip;
  float* bufA = xw0 + (size_t)N * FDIM;
  float* bufB = bufA + (size_t)4 * N * FDIM;
  float* Harr = bufB + (size_t)4 * N * FDIM;
  float* cmax  = Harr + (size_t)N * NSDIM;
  float* cden  = cmax + NSDIM;
  float* hyperT = cden + NSDIM;                        // NS*F
  float* hpart  = hyperT + NSDIM * FDIM;               // HPART * NS*F (8 MB)
  float* hpart2 = hpart + (size_t)HPART * NSDIM * FDIM; // HGRP * NS*F (512 KB)

  float* out0 = (float*)d_out;             // H_soft (N,NS)
  float* out1 = out0 + (size_t)N * NSDIM;  // hyper (NS,F)
  float* out2 = out1 + NSDIM * FDIM;       // dots (4N,NS)

  const int BLK = 256;
  const int WPB = BLK / 64;
  const int ntiles = (N + 255) / 256;
  auto wgrid = [](int items, int wpb) { return (items + wpb - 1) / wpb; };
  auto tgrid = [](int rows) { return (rows + 255) / 256; };
  const int ngrp = (N + 3) / 4;

  // zero: bucket counts, hist5, Harr
  hipMemsetAsync(bkcntS, 0, 512 * sizeof(int), stream);
  hipMemsetAsync(hist5, 0, (size_t)5 * NSDIM * sizeof(int), stream);
  hipMemsetAsync(Harr, 0, (size_t)N * NSDIM * sizeof(float), stream);

  // --- src-CSR (bucket-staged) ---
  bkhist2_k<<<256, BLK, 0, stream>>>(src, dst, bkcntS, bkcntD, E);
  bkscan2_k<<<1, 256, 0, stream>>>(bkcntS, bkcntD, bkoffS, bkcurS, bkoffD, bkcurD, NB);
  bkfillS_k<<<(E + 2047) / 2048, BLK, 0, stream>>>(src, dst, bkcurS, ebuf, E);
  cntfillS_k<<<NB, BLK, 0, stream>>>(ebuf, bkoffS, cntS, N);
  scanA_k<<<ntiles, 256, 0, stream>>>(cntS, rowoffS, tilesum, N);
  scanB_k<<<1, 256, 0, stream>>>(tilesum, tileoff, ntiles);
  scanC_k<<<ntiles, 256, 0, stream>>>(rowoffS, cntS, tileoff, N, ntiles);
  csrfill_k<<<NB, BLK, 0, stream>>>(ebuf, bkoffS, rowoffS, slots, N);

  // --- G + mask (ebuf dead; G overwrites it) ---
  {
    dim3 g(tgrid(N), TREP);
    gmat_k<<<g, BLK, 0, stream>>>(features, W_lin, b_lin, G, N);
  }
  mask_k<<<wgrid(ngrp, WPB), BLK, 0, stream>>>(rowoffS, slots, G, features, N);

  // --- dst-CSR (bucket-staged; ebuf overwrites dead G) ---
  bkfillD_k<<<NB, BLK, 0, stream>>>(rowoffS, slots, bkcurD, ebuf, N);
  cntfillD_k<<<NB, BLK, 0, stream>>>(ebuf, bkoffD, cntD, cntR, N);
  dinv_k<<<(4 * N + BLK - 1) / BLK, BLK, 0, stream>>>(cntD, cntR, dinv, N);
  scanA_k<<<ntiles, 256, 0, stream>>>(cntD, rowoffD, tilesum, N);
  scanB_k<<<1, 256, 0, stream>>>(tilesum, tileoff, ntiles);
  scanC_k<<<ntiles, 256, 0, stream>>>(rowoffD, cntD, tileoff, N, ntiles);
  csrfill_k<<<NB, BLK, 0, stream>>>(ebuf, bkoffD, rowoffD, slots + E, N);

  // --- GCN layers (xws overwrites dead ebuf) ---
  gemm_k<true><<<tgrid(N), BLK, 0, stream>>>(features, gcn0_W, xw0, N, xws, dinv, N);
  gather_finish_k<true, true><<<wgrid(ngrp, WPB), BLK, 0, stream>>>(
      rowoffD, slots + E, xws, xw0, dinv, gcn0_b, bufA, N);
  gemm_k<false><<<tgrid(4 * N), BLK, 0, stream>>>(bufA, gcn1_W, bufB, 4 * N, xws, dinv, N);
  gather_finish_k<false, false><<<wgrid(ngrp, WPB), BLK, 0, stream>>>(
      rowoffD, slots + E, xws, bufB, dinv, gcn1_b, bufA, N);

  // --- head ---
  logits_k<<<tgrid(4 * N), BLK, 0, stream>>>(bufA, lin1_W, lin1_b, Harr, 4 * N, N);
  hyper1_k<<<HPART, BLK, 0, stream>>>(Harr, bufA, hpart, N);
  {
    dim3 g2a(NSDIM * FDIM / 256, HGRP);
    hyper2a_k<<<g2a, 256, 0, stream>>>(hpart, hpart2);
  }
  hyper2b_k<<<NSDIM * FDIM / 256, 256, 0, stream>>>(hpart2, out1, hyperT);
  colhist_k<<<256, BLK, 0, stream>>>(Harr, hist5, N);
  colfin_k<<<1, 64, 0, stream>>>(hist5, cmax, cden);
  hsoft_k<<<(N * NSDIM + BLK - 1) / BLK, BLK, 0, stream>>>(Harr, cmax, cden, out0, N);
  dots_k<<<tgrid(N), BLK, 0, stream>>>(features, hyperT, out2, N);
}

// Round 15
// 496.354 us; speedup vs baseline: 1.3092x; 1.3092x over previous
//
#include <hip/hip_runtime.h>

#define FDIM 64
#define NSDIM 64
#define TREP 3
#define EPSV 1e-8f
#define HPART 512   // hyper stage-1 partials
#define HGRP  32    // stage-2a groups (HPART/16)

// ============================================================================
// Register-tile GEMM family (one lane = one output row; W via scalar path)
// k-loop unroll 4: ~4 row loads in flight, modest VGPR cost.
// ============================================================================

__global__ __launch_bounds__(256) void gmat_k(const float* __restrict__ X,
                                              const float* __restrict__ W,
                                              const float* __restrict__ B,
                                              float* __restrict__ G, int nN)
{
  const int t    = blockIdx.y;
  const int lane = threadIdx.x & 63;
  const int wib  = threadIdx.x >> 6;
  const int row  = blockIdx.x * 256 + wib * 64 + lane;
  const float* __restrict__ Wt = W + (size_t)t * FDIM * FDIM;
  const float* __restrict__ Bt = B + t * FDIM;
  float acc[FDIM];
#pragma unroll
  for (int c = 0; c < FDIM; ++c) acc[c] = Bt[c];
  if (row >= nN) return;
  const float4* __restrict__ xr = (const float4*)(X + (size_t)row * FDIM);
  float ss = 0.f;
#pragma unroll 4
  for (int kk = 0; kk < FDIM / 4; ++kk) {
    const float4 xv = xr[kk];
    ss = fmaf(xv.x, xv.x, fmaf(xv.y, xv.y, fmaf(xv.z, xv.z, fmaf(xv.w, xv.w, ss))));
    const float* __restrict__ w0 = Wt + (kk * 4 + 0) * FDIM;
    const float* __restrict__ w1 = Wt + (kk * 4 + 1) * FDIM;
    const float* __restrict__ w2 = Wt + (kk * 4 + 2) * FDIM;
    const float* __restrict__ w3 = Wt + (kk * 4 + 3) * FDIM;
#pragma unroll
    for (int c = 0; c < FDIM; ++c) acc[c] = fmaf(xv.x, w0[c], acc[c]);
#pragma unroll
    for (int c = 0; c < FDIM; ++c) acc[c] = fmaf(xv.y, w1[c], acc[c]);
#pragma unroll
    for (int c = 0; c < FDIM; ++c) acc[c] = fmaf(xv.z, w2[c], acc[c]);
#pragma unroll
    for (int c = 0; c < FDIM; ++c) acc[c] = fmaf(xv.w, w3[c], acc[c]);
  }
  float sq = 0.f;
#pragma unroll
  for (int c = 0; c < FDIM; ++c) sq = fmaf(acc[c], acc[c], sq);
  const float nf = fmaxf(sqrtf(ss), EPSV);
  const float na = fmaxf(sqrtf(sq), EPSV);
  float* __restrict__ grow = G + ((size_t)t * nN + row) * FDIM;
#pragma unroll
  for (int c4 = 0; c4 < FDIM / 4; ++c4) {
    const float4 xv = xr[c4];
    ((float4*)grow)[c4] = make_float4(
        fmaf(nf, acc[4 * c4 + 0], -na * xv.x),
        fmaf(nf, acc[4 * c4 + 1], -na * xv.y),
        fmaf(nf, acc[4 * c4 + 2], -na * xv.z),
        fmaf(nf, acc[4 * c4 + 3], -na * xv.w));
  }
}

template<bool RELU_IN>
__global__ __launch_bounds__(256) void gemm_k(const float* __restrict__ X,
                                              const float* __restrict__ W,
                                              float* __restrict__ out, int rows,
                                              float* __restrict__ scaled,
                                              const float* __restrict__ dinv, int nScaled)
{
  const int lane = threadIdx.x & 63;
  const int wib  = threadIdx.x >> 6;
  const int row  = blockIdx.x * 256 + wib * 64 + lane;
  if (row >= rows) return;
  float acc[FDIM];
#pragma unroll
  for (int c = 0; c < FDIM; ++c) acc[c] = 0.f;
  const float4* __restrict__ xr = (const float4*)(X + (size_t)row * FDIM);
#pragma unroll 4
  for (int kk = 0; kk < FDIM / 4; ++kk) {
    float4 xv = xr[kk];
    if (RELU_IN) {
      xv.x = fmaxf(xv.x, 0.f); xv.y = fmaxf(xv.y, 0.f);
      xv.z = fmaxf(xv.z, 0.f); xv.w = fmaxf(xv.w, 0.f);
    }
    const float* __restrict__ w0 = W + (kk * 4 + 0) * FDIM;
    const float* __restrict__ w1 = W + (kk * 4 + 1) * FDIM;
    const float* __restrict__ w2 = W + (kk * 4 + 2) * FDIM;
    const float* __restrict__ w3 = W + (kk * 4 + 3) * FDIM;
#pragma unroll
    for (int c = 0; c < FDIM; ++c) acc[c] = fmaf(xv.x, w0[c], acc[c]);
#pragma unroll
    for (int c = 0; c < FDIM; ++c) acc[c] = fmaf(xv.y, w1[c], acc[c]);
#pragma unroll
    for (int c = 0; c < FDIM; ++c) acc[c] = fmaf(xv.z, w2[c], acc[c]);
#pragma unroll
    for (int c = 0; c < FDIM; ++c) acc[c] = fmaf(xv.w, w3[c], acc[c]);
  }
  float* __restrict__ orow = out + (size_t)row * FDIM;
#pragma unroll
  for (int c4 = 0; c4 < FDIM / 4; ++c4)
    ((float4*)orow)[c4] = make_float4(acc[4 * c4], acc[4 * c4 + 1],
                                      acc[4 * c4 + 2], acc[4 * c4 + 3]);
  if (scaled != nullptr && row < nScaled) {
    const float dv = dinv[row];
    float* __restrict__ srow = scaled + (size_t)row * FDIM;
#pragma unroll
    for (int c4 = 0; c4 < FDIM / 4; ++c4)
      ((float4*)srow)[c4] = make_float4(acc[4 * c4] * dv, acc[4 * c4 + 1] * dv,
                                        acc[4 * c4 + 2] * dv, acc[4 * c4 + 3] * dv);
  }
}

__global__ __launch_bounds__(256) void logits_k(const float* __restrict__ X,
                                                const float* __restrict__ W,
                                                const float* __restrict__ B,
                                                float* __restrict__ H,
                                                int rows, int nN)
{
  const int lane = threadIdx.x & 63;
  const int wib  = threadIdx.x >> 6;
  const int row  = blockIdx.x * 256 + wib * 64 + lane;
  float acc[NSDIM];
#pragma unroll
  for (int c = 0; c < NSDIM; ++c) acc[c] = B[c];
  if (row >= rows) return;
  const float4* __restrict__ xr = (const float4*)(X + (size_t)row * FDIM);
#pragma unroll 4
  for (int kk = 0; kk < FDIM / 4; ++kk) {
    float4 xv = xr[kk];
    xv.x = fmaxf(xv.x, 0.f); xv.y = fmaxf(xv.y, 0.f);
    xv.z = fmaxf(xv.z, 0.f); xv.w = fmaxf(xv.w, 0.f);
    const float* __restrict__ w0 = W + (kk * 4 + 0) * NSDIM;
    const float* __restrict__ w1 = W + (kk * 4 + 1) * NSDIM;
    const float* __restrict__ w2 = W + (kk * 4 + 2) * NSDIM;
    const float* __restrict__ w3 = W + (kk * 4 + 3) * NSDIM;
#pragma unroll
    for (int c = 0; c < NSDIM; ++c) acc[c] = fmaf(xv.x, w0[c], acc[c]);
#pragma unroll
    for (int c = 0; c < NSDIM; ++c) acc[c] = fmaf(xv.y, w1[c], acc[c]);
#pragma unroll
    for (int c = 0; c < NSDIM; ++c) acc[c] = fmaf(xv.z, w2[c], acc[c]);
#pragma unroll
    for (int c = 0; c < NSDIM; ++c) acc[c] = fmaf(xv.w, w3[c], acc[c]);
  }
  float bv = acc[0]; int bi = 0;
#pragma unroll
  for (int c = 1; c < NSDIM; ++c)
    if (acc[c] > bv) { bv = acc[c]; bi = c; }   // strict > : first-index tiebreak
  int v = row;
  while (v >= nN) v -= nN;
  atomicAdd(&H[(size_t)v * NSDIM + bi], 1.f);
}

__global__ __launch_bounds__(256) void dots_k(const float* __restrict__ X,
                                              const float* __restrict__ WT,
                                              float* __restrict__ out2, int nN)
{
  const int lane = threadIdx.x & 63;
  const int wib  = threadIdx.x >> 6;
  const int row  = blockIdx.x * 256 + wib * 64 + lane;
  if (row >= nN) return;
  float acc[NSDIM];
#pragma unroll
  for (int c = 0; c < NSDIM; ++c) acc[c] = 0.f;
  const float4* __restrict__ xr = (const float4*)(X + (size_t)row * FDIM);
#pragma unroll 4
  for (int kk = 0; kk < FDIM / 4; ++kk) {
    const float4 xv = xr[kk];
    const float* __restrict__ w0 = WT + (kk * 4 + 0) * NSDIM;
    const float* __restrict__ w1 = WT + (kk * 4 + 1) * NSDIM;
    const float* __restrict__ w2 = WT + (kk * 4 + 2) * NSDIM;
    const float* __restrict__ w3 = WT + (kk * 4 + 3) * NSDIM;
#pragma unroll
    for (int c = 0; c < NSDIM; ++c) acc[c] = fmaf(xv.x, w0[c], acc[c]);
#pragma unroll
    for (int c = 0; c < NSDIM; ++c) acc[c] = fmaf(xv.y, w1[c], acc[c]);
#pragma unroll
    for (int c = 0; c < NSDIM; ++c) acc[c] = fmaf(xv.z, w2[c], acc[c]);
#pragma unroll
    for (int c = 0; c < NSDIM; ++c) acc[c] = fmaf(xv.w, w3[c], acc[c]);
  }
#pragma unroll
  for (int c = 0; c < NSDIM; ++c) acc[c] *= 0.125f;
#pragma unroll
  for (int b = 0; b < 4; ++b) {
    float* __restrict__ orow = out2 + ((size_t)b * nN + row) * NSDIM;
#pragma unroll
    for (int c4 = 0; c4 < NSDIM / 4; ++c4)
      ((float4*)orow)[c4] = make_float4(acc[4 * c4], acc[4 * c4 + 1],
                                        acc[4 * c4 + 2], acc[4 * c4 + 3]);
  }
}

// ============================================================================
// Bucket-staged CSR build (atomic-light, write-clean)
// ============================================================================

__global__ __launch_bounds__(256) void bkhist2_k(const int* __restrict__ src,
                                                 const int* __restrict__ dst,
                                                 int* __restrict__ bkcntS,
                                                 int* __restrict__ bkcntD, int nE)
{
  __shared__ int hs[256], hd[256];
  const int tid = threadIdx.x;
  hs[tid] = 0; hd[tid] = 0;
  __syncthreads();
  for (int e = blockIdx.x * 256 + tid; e < nE; e += gridDim.x * 256) {
    atomicAdd(&hs[src[e] >> 8], 1);
    atomicAdd(&hd[dst[e] >> 8], 1);
  }
  __syncthreads();
  if (hs[tid]) atomicAdd(&bkcntS[tid], hs[tid]);
  if (hd[tid]) atomicAdd(&bkcntD[tid], hd[tid]);
}

__global__ __launch_bounds__(256) void bkscan2_k(const int* __restrict__ cS,
                                                 const int* __restrict__ cD,
                                                 int* __restrict__ offS, int* __restrict__ curS,
                                                 int* __restrict__ offD, int* __restrict__ curD,
                                                 int NB)
{
  __shared__ int s[256];
  const int tid = threadIdx.x;
  int v = (tid < NB) ? cS[tid] : 0;
  s[tid] = v; __syncthreads();
#pragma unroll
  for (int o = 1; o < 256; o <<= 1) {
    const int t = (tid >= o) ? s[tid - o] : 0;
    __syncthreads(); s[tid] += t; __syncthreads();
  }
  if (tid < NB) { offS[tid] = s[tid] - v; curS[tid] = s[tid] - v; }
  if (tid == 255) offS[NB] = s[255];
  __syncthreads();
  v = (tid < NB) ? cD[tid] : 0;
  s[tid] = v; __syncthreads();
#pragma unroll
  for (int o = 1; o < 256; o <<= 1) {
    const int t = (tid >= o) ? s[tid - o] : 0;
    __syncthreads(); s[tid] += t; __syncthreads();
  }
  if (tid < NB) { offD[tid] = s[tid] - v; curD[tid] = s[tid] - v; }
  if (tid == 255) offD[NB] = s[255];
}

__global__ __launch_bounds__(256) void bkfillS_k(const int* __restrict__ src,
                                                 const int* __restrict__ dst,
                                                 int* __restrict__ bkcur,
                                                 uint2* __restrict__ ebuf, int nE)
{
  __shared__ int hist[256], gbase[256];
  const int tid = threadIdx.x;
  for (int cb = blockIdx.x * 2048; cb < nE; cb += gridDim.x * 2048) {
    hist[tid] = 0;
    __syncthreads();
    int bk[8], ofs[8], sv[8], dv[8];
#pragma unroll
    for (int k = 0; k < 8; ++k) {
      const int i = cb + k * 256 + tid;
      bk[k] = -1;
      if (i < nE) {
        sv[k] = src[i];
        dv[k] = dst[i];
        bk[k] = sv[k] >> 8;
        ofs[k] = atomicAdd(&hist[bk[k]], 1);
      }
    }
    __syncthreads();
    if (hist[tid] > 0) gbase[tid] = atomicAdd(&bkcur[tid], hist[tid]);
    __syncthreads();
#pragma unroll
    for (int k = 0; k < 8; ++k)
      if (bk[k] >= 0)
        ebuf[gbase[bk[k]] + ofs[k]] = make_uint2((unsigned)sv[k], (unsigned)dv[k]);
    __syncthreads();
  }
}

__global__ __launch_bounds__(256) void cntfillS_k(const uint2* __restrict__ ebuf,
                                                  const int* __restrict__ bkoff,
                                                  int* __restrict__ cnt, int nN)
{
  __shared__ int h[256];
  const int tid = threadIdx.x, b = blockIdx.x;
  h[tid] = 0; __syncthreads();
  const int lo = bkoff[b], hi = bkoff[b + 1];
  for (int i = lo + tid; i < hi; i += 256)
    atomicAdd(&h[ebuf[i].x & 255u], 1);
  __syncthreads();
  const int node = b * 256 + tid;
  if (node < nN) cnt[node] = h[tid];
}

__global__ __launch_bounds__(256) void scanA_k(const int* __restrict__ cnt,
                                               int* __restrict__ rowoff,
                                               int* __restrict__ tilesum, int nTot)
{
  __shared__ int s[256];
  const int i = blockIdx.x * 256 + threadIdx.x;
  const int v = (i < nTot) ? cnt[i] : 0;
  s[threadIdx.x] = v;
  __syncthreads();
#pragma unroll
  for (int o = 1; o < 256; o <<= 1) {
    const int t = (threadIdx.x >= o) ? s[threadIdx.x - o] : 0;
    __syncthreads();
    s[threadIdx.x] += t;
    __syncthreads();
  }
  if (i < nTot) rowoff[i] = s[threadIdx.x] - v;
  if (threadIdx.x == 255) tilesum[blockIdx.x] = s[255];
}

__global__ __launch_bounds__(256) void scanB_k(const int* __restrict__ tilesum,
                                               int* __restrict__ tileoff, int ntiles)
{
  __shared__ int s[256];
  __shared__ int carry;
  if (threadIdx.x == 0) carry = 0;
  __syncthreads();
  for (int base = 0; base < ntiles; base += 256) {
    const int idx = base + threadIdx.x;
    const int v = (idx < ntiles) ? tilesum[idx] : 0;
    s[threadIdx.x] = v;
    __syncthreads();
#pragma unroll
    for (int o = 1; o < 256; o <<= 1) {
      const int t = (threadIdx.x >= o) ? s[threadIdx.x - o] : 0;
      __syncthreads();
      s[threadIdx.x] += t;
      __syncthreads();
    }
    if (idx < ntiles) tileoff[idx] = carry + s[threadIdx.x] - v;
    __syncthreads();
    if (threadIdx.x == 0) carry += s[255];
    __syncthreads();
  }
  if (threadIdx.x == 0) tileoff[ntiles] = carry;
}

__global__ __launch_bounds__(256) void scanC_k(int* __restrict__ rowoff,
                                               int* __restrict__ cursor,
                                               const int* __restrict__ tileoff,
                                               int nTot, int ntiles)
{
  const int i = blockIdx.x * 256 + threadIdx.x;
  if (i < nTot) {
    const int v = rowoff[i] + tileoff[i >> 8];
    rowoff[i] = v;
    cursor[i] = v;
  }
  if (i == 0) rowoff[nTot] = tileoff[ntiles];
}

__global__ __launch_bounds__(256) void csrfill_k(const uint2* __restrict__ ebuf,
                                                 const int* __restrict__ bkoff,
                                                 const int* __restrict__ rowoff,
                                                 unsigned* __restrict__ out, int nN)
{
  __shared__ int cur[256];
  const int tid = threadIdx.x, b = blockIdx.x;
  const int node = b * 256 + tid;
  cur[tid] = (node < nN) ? rowoff[node] : 0;
  __syncthreads();
  const int lo = bkoff[b], hi = bkoff[b + 1];
  for (int i = lo + tid; i < hi; i += 256) {
    const uint2 p = ebuf[i];
    const int pos = atomicAdd(&cur[(int)(p.x & 255u)], 1);
    out[pos] = p.y;
  }
}

// ---------- mask (no atomics): group-per-source, 2 edges in flight ----------
__global__ void mask_k(const int* __restrict__ rowoffS, unsigned* __restrict__ slots,
                       const float* __restrict__ G, const float* __restrict__ f, int nN)
{
  const int lane  = threadIdx.x & 63;
  const int glane = lane & 15;
  const int grp   = lane >> 4;
  const int wib   = threadIdx.x >> 6;
  const int wpb   = blockDim.x >> 6;
  const float4* __restrict__ G4 = (const float4*)G;
  const float4* __restrict__ f4 = (const float4*)f;
  const int nwave = gridDim.x * wpb;
  for (int sbase = (blockIdx.x * wpb + wib) * 4; sbase < nN; sbase += nwave * 4) {
    const int s = sbase + grp;
    const bool sv = s < nN;
    const int ss = sv ? s : 0;
    const int start = rowoffS[ss];
    const int end   = sv ? rowoffS[ss + 1] : start;
    const float4 g0 = G4[((size_t)0 * nN + ss) * 16 + glane];
    const float4 g1 = G4[((size_t)1 * nN + ss) * 16 + glane];
    const float4 g2 = G4[((size_t)2 * nN + ss) * 16 + glane];
    int base = start;
    for (; base + 2 <= end; base += 2) {
      const unsigned w0 = slots[base + 0] & 0xFFFFFu;
      const unsigned w1 = slots[base + 1] & 0xFFFFFu;
      const float4 fv0 = f4[(size_t)w0 * 16 + glane];
      const float4 fv1 = f4[(size_t)w1 * 16 + glane];
      float p00 = fmaf(fv0.x, g0.x, fmaf(fv0.y, g0.y, fmaf(fv0.z, g0.z, fv0.w * g0.w)));
      float p01 = fmaf(fv0.x, g1.x, fmaf(fv0.y, g1.y, fmaf(fv0.z, g1.z, fv0.w * g1.w)));
      float p02 = fmaf(fv0.x, g2.x, fmaf(fv0.y, g2.y, fmaf(fv0.z, g2.z, fv0.w * g2.w)));
      float p10 = fmaf(fv1.x, g0.x, fmaf(fv1.y, g0.y, fmaf(fv1.z, g0.z, fv1.w * g0.w)));
      float p11 = fmaf(fv1.x, g1.x, fmaf(fv1.y, g1.y, fmaf(fv1.z, g1.z, fv1.w * g1.w)));
      float p12 = fmaf(fv1.x, g2.x, fmaf(fv1.y, g2.y, fmaf(fv1.z, g2.z, fv1.w * g2.w)));
#pragma unroll
      for (int o = 8; o > 0; o >>= 1) {
        p00 += __shfl_xor(p00, o); p01 += __shfl_xor(p01, o); p02 += __shfl_xor(p02, o);
        p10 += __shfl_xor(p10, o); p11 += __shfl_xor(p11, o); p12 += __shfl_xor(p12, o);
      }
      if (glane == 0) {
        const unsigned m0 = (p00 > 0.f ? 1u : 0u) | (p01 > 0.f ? 2u : 0u) | (p02 > 0.f ? 4u : 0u);
        const unsigned m1 = (p10 > 0.f ? 1u : 0u) | (p11 > 0.f ? 2u : 0u) | (p12 > 0.f ? 4u : 0u);
        if (m0) slots[base + 0] = w0 | (m0 << 20);
        if (m1) slots[base + 1] = w1 | (m1 << 20);
      }
    }
    if (base < end) {
      const unsigned d = slots[base] & 0xFFFFFu;
      const float4 fv = f4[(size_t)d * 16 + glane];
      float p0 = fmaf(fv.x, g0.x, fmaf(fv.y, g0.y, fmaf(fv.z, g0.z, fv.w * g0.w)));
      float p1 = fmaf(fv.x, g1.x, fmaf(fv.y, g1.y, fmaf(fv.z, g1.z, fv.w * g1.w)));
      float p2 = fmaf(fv.x, g2.x, fmaf(fv.y, g2.y, fmaf(fv.z, g2.z, fv.w * g2.w)));
#pragma unroll
      for (int o = 8; o > 0; o >>= 1) {
        p0 += __shfl_xor(p0, o);
        p1 += __shfl_xor(p1, o);
        p2 += __shfl_xor(p2, o);
      }
      if (glane == 0) {
        unsigned m = (p0 > 0.f ? 1u : 0u) | (p1 > 0.f ? 2u : 0u) | (p2 > 0.f ? 4u : 0u);
        if (m) slots[base] = d | (m << 20);
      }
    }
  }
}

__global__ __launch_bounds__(256) void bkfillD_k(const int* __restrict__ rowoffS,
                                                 const unsigned* __restrict__ slots,
                                                 int* __restrict__ bkcur,
                                                 uint2* __restrict__ ebuf, int nN)
{
  __shared__ int roff[257];
  __shared__ int hist[256], gbase[256];
  const int tid = threadIdx.x;
  const int sb  = blockIdx.x;
  const int nb0 = sb * 256;
  {
    int idx = nb0 + tid; if (idx > nN) idx = nN;
    roff[tid] = rowoffS[idx];
    if (tid == 0) { int e = nb0 + 256; if (e > nN) e = nN; roff[256] = rowoffS[e]; }
  }
  __syncthreads();
  const int estart = roff[0], eend = roff[256];
  for (int cb = estart; cb < eend; cb += 2048) {
    hist[tid] = 0;
    __syncthreads();
    int bk[8], ofs[8]; unsigned dv[8], pv[8];
#pragma unroll
    for (int k = 0; k < 8; ++k) {
      const int i = cb + k * 256 + tid;
      bk[k] = -1;
      if (i < eend) {
        const unsigned v = slots[i];
        const unsigned d = v & 0xFFFFFu;
        int lo = 0, hi = 256;
#pragma unroll
        for (int st = 0; st < 8; ++st) {
          const int mid = (lo + hi) >> 1;
          if (roff[mid] <= i) lo = mid; else hi = mid;
        }
        dv[k] = d;
        pv[k] = (unsigned)(nb0 + lo) | (v & 0xFFF00000u);
        bk[k] = (int)(d >> 8);
        ofs[k] = atomicAdd(&hist[bk[k]], 1);
      }
    }
    __syncthreads();
    if (hist[tid] > 0) gbase[tid] = atomicAdd(&bkcur[tid], hist[tid]);
    __syncthreads();
#pragma unroll
    for (int k = 0; k < 8; ++k)
      if (bk[k] >= 0) ebuf[gbase[bk[k]] + ofs[k]] = make_uint2(dv[k], pv[k]);
    __syncthreads();
  }
}

__global__ __launch_bounds__(256) void cntfillD_k(const uint2* __restrict__ ebuf,
                                                  const int* __restrict__ bkoff,
                                                  int* __restrict__ cntD,
                                                  int* __restrict__ cntR, int nN)
{
  __shared__ int h0[256], h1[256], h2[256], h3[256];
  const int tid = threadIdx.x, b = blockIdx.x;
  h0[tid] = 0; h1[tid] = 0; h2[tid] = 0; h3[tid] = 0;
  __syncthreads();
  const int lo = bkoff[b], hi = bkoff[b + 1];
  for (int i = lo + tid; i < hi; i += 256) {
    const uint2 p = ebuf[i];
    const int l = (int)(p.x & 255u);
    const unsigned m = p.y >> 20;
    atomicAdd(&h0[l], 1);
    if (m & 1u) atomicAdd(&h1[l], 1);
    if (m & 2u) atomicAdd(&h2[l], 1);
    if (m & 4u) atomicAdd(&h3[l], 1);
  }
  __syncthreads();
  const int node = b * 256 + tid;
  if (node < nN) {
    cntD[node] = h0[tid];
    cntR[node] = h1[tid];
    cntR[nN + node] = h2[tid];
    cntR[2 * nN + node] = h3[tid];
  }
}

__global__ void dinv_k(const int* __restrict__ cntD0, const int* __restrict__ cntR,
                       float* __restrict__ dinv, int nN)
{
  int i = blockIdx.x * blockDim.x + threadIdx.x;
  int tot = 4 * nN;
  if (i < tot) {
    float deg = (i < nN) ? ((float)cntD0[i] + 1.f) : ((float)cntR[i - nN] + 2.f);
    dinv[i] = 1.f / sqrtf(deg);
  }
}

// ---------- fused CSR gather + GCN finish (group-per-destination, float4 path) ----------
template<bool L0, bool RELU>
__global__ void gather_finish_k(const int* __restrict__ rowoff, const unsigned* __restrict__ csr,
                                const float* __restrict__ xws, const float* __restrict__ xw,
                                const float* __restrict__ dinv, const float* __restrict__ bias,
                                float* __restrict__ out, int nN)
{
  const int lane  = threadIdx.x & 63;
  const int glane = lane & 15;
  const int grp   = lane >> 4;
  const int wib   = threadIdx.x >> 6;
  const int wpb   = blockDim.x >> 6;
  const float4* __restrict__ xws4 = (const float4*)xws;
  const float4* __restrict__ xw4  = (const float4*)xw;
  float4* __restrict__ out4 = (float4*)out;
  const float4 b4 = ((const float4*)bias)[glane];
  const int nwave = gridDim.x * wpb;
  for (int dbase = (blockIdx.x * wpb + wib) * 4; dbase < nN; dbase += nwave * 4) {
    const int d = dbase + grp;
    const bool dv = d < nN;
    const int dd = dv ? d : 0;
    const int start = rowoff[dd];
    const int end   = dv ? rowoff[dd + 1] : start;
    float4 A0 = make_float4(0.f, 0.f, 0.f, 0.f);
    float4 A1 = A0, A2 = A0, A3 = A0;
    int j = start;
    for (; j + 4 <= end; j += 4) {
      const unsigned c0 = csr[j + 0], c1 = csr[j + 1], c2 = csr[j + 2], c3 = csr[j + 3];
      const float4 v0 = xws4[(size_t)(c0 & 0xFFFFFu) * 16 + glane];
      const float4 v1 = xws4[(size_t)(c1 & 0xFFFFFu) * 16 + glane];
      const float4 v2 = xws4[(size_t)(c2 & 0xFFFFFu) * 16 + glane];
      const float4 v3 = xws4[(size_t)(c3 & 0xFFFFFu) * 16 + glane];
      A0.x += v0.x; A0.y += v0.y; A0.z += v0.z; A0.w += v0.w;
      if (c0 & 0x100000u) { A1.x += v0.x; A1.y += v0.y; A1.z += v0.z; A1.w += v0.w; }
      if (c0 & 0x200000u) { A2.x += v0.x; A2.y += v0.y; A2.z += v0.z; A2.w += v0.w; }
      if (c0 & 0x400000u) { A3.x += v0.x; A3.y += v0.y; A3.z += v0.z; A3.w += v0.w; }
      A0.x += v1.x; A0.y += v1.y; A0.z += v1.z; A0.w += v1.w;
      if (c1 & 0x100000u) { A1.x += v1.x; A1.y += v1.y; A1.z += v1.z; A1.w += v1.w; }
      if (c1 & 0x200000u) { A2.x += v1.x; A2.y += v1.y; A2.z += v1.z; A2.w += v1.w; }
      if (c1 & 0x400000u) { A3.x += v1.x; A3.y += v1.y; A3.z += v1.z; A3.w += v1.w; }
      A0.x += v2.x; A0.y += v2.y; A0.z += v2.z; A0.w += v2.w;
      if (c2 & 0x100000u) { A1.x += v2.x; A1.y += v2.y; A1.z += v2.z; A1.w += v2.w; }
      if (c2 & 0x200000u) { A2.x += v2.x; A2.y += v2.y; A2.z += v2.z; A2.w += v2.w; }
      if (c2 & 0x400000u) { A3.x += v2.x; A3.y += v2.y; A3.z += v2.z; A3.w += v2.w; }
      A0.x += v3.x; A0.y += v3.y; A0.z += v3.z; A0.w += v3.w;
      if (c3 & 0x100000u) { A1.x += v3.x; A1.y += v3.y; A1.z += v3.z; A1.w += v3.w; }
      if (c3 & 0x200000u) { A2.x += v3.x; A2.y += v3.y; A2.z += v3.z; A2.w += v3.w; }
      if (c3 & 0x400000u) { A3.x += v3.x; A3.y += v3.y; A3.z += v3.z; A3.w += v3.w; }
    }
    for (; j < end; ++j) {
      const unsigned c0 = csr[j];
      const float4 v0 = xws4[(size_t)(c0 & 0xFFFFFu) * 16 + glane];
      A0.x += v0.x; A0.y += v0.y; A0.z += v0.z; A0.w += v0.w;
      if (c0 & 0x100000u) { A1.x += v0.x; A1.y += v0.y; A1.z += v0.z; A1.w += v0.w; }
      if (c0 & 0x200000u) { A2.x += v0.x; A2.y += v0.y; A2.z += v0.z; A2.w += v0.w; }
      if (c0 & 0x400000u) { A3.x += v0.x; A3.y += v0.y; A3.z += v0.z; A3.w += v0.w; }
    }
    if (!dv) continue;
    const float di0 = dinv[d];
    const float4 xs  = xws4[(size_t)d * 16 + glane];
    const float4 xb0 = xw4[(size_t)d * 16 + glane];

    float4 r0;
    r0.x = fmaf(A0.x + xs.x, di0, b4.x);
    r0.y = fmaf(A0.y + xs.y, di0, b4.y);
    r0.z = fmaf(A0.z + xs.z, di0, b4.z);
    r0.w = fmaf(A0.w + xs.w, di0, b4.w);
    if (RELU) {
      r0.x = fmaxf(r0.x, 0.f); r0.y = fmaxf(r0.y, 0.f);
      r0.z = fmaxf(r0.z, 0.f); r0.w = fmaxf(r0.w, 0.f);
    }
    out4[(size_t)d * 16 + glane] = r0;

#pragma unroll
    for (int t = 1; t <= 3; ++t) {
      const float4 At = (t == 1) ? A1 : (t == 2) ? A2 : A3;
      const float dit = dinv[t * nN + d];
      const float4 self = L0 ? xb0 : xw4[((size_t)t * nN + d) * 16 + glane];
      float4 r;
      r.x = fmaf(At.x + xs.x + self.x * dit, dit, b4.x);
      r.y = fmaf(At.y + xs.y + self.y * dit, dit, b4.y);
      r.z = fmaf(At.z + xs.z + self.z * dit, dit, b4.z);
      r.w = fmaf(At.w + xs.w + self.w * dit, dit, b4.w);
      if (RELU) {
        r.x = fmaxf(r.x, 0.f); r.y = fmaxf(r.y, 0.f);
        r.z = fmaxf(r.z, 0.f); r.w = fmaxf(r.w, 0.f);
      }
      out4[((size_t)t * nN + d) * 16 + glane] = r;
    }
  }
}

// ---------- hyper stage 1: per-block LDS accumulate -> private partial ----------
__global__ __launch_bounds__(256) void hyper1_k(const float* __restrict__ H,
                                                const float* __restrict__ x2,
                                                float* __restrict__ partial, int nN)
{
  __shared__ float hl[NSDIM * FDIM];
  for (int i = threadIdx.x; i < NSDIM * FDIM; i += blockDim.x) hl[i] = 0.f;
  __syncthreads();
  const int lane = threadIdx.x & 63;
  const int wib  = threadIdx.x >> 6;
  const int wpb  = blockDim.x >> 6;
  for (int i = blockIdx.x * wpb + wib; i < nN; i += gridDim.x * wpb) {
    float hv = H[(size_t)i * NSDIM + lane];
    unsigned long long ball = __ballot(hv > 0.f);
    float x = x2[(size_t)i * FDIM + lane];
    while (ball) {
      int j = __ffsll((unsigned long long)ball) - 1;
      ball &= ball - 1;
      atomicAdd(&hl[j * FDIM + lane], x);
    }
  }
  __syncthreads();
  float* __restrict__ po = partial + (size_t)blockIdx.x * NSDIM * FDIM;
  for (int i = threadIdx.x; i < NSDIM * FDIM; i += blockDim.x)
    po[i] = hl[i];
}

// ---------- hyper stage 2a ----------
__global__ __launch_bounds__(256) void hyper2a_k(const float* __restrict__ partial,
                                                 float* __restrict__ part2)
{
  const int idx = blockIdx.x * 256 + threadIdx.x;   // [0,4096)
  const int g   = blockIdx.y;                       // [0,HGRP)
  const float* __restrict__ p = partial + ((size_t)g * 16) * (NSDIM * FDIM) + idx;
  float s0 = 0.f, s1 = 0.f, s2 = 0.f, s3 = 0.f;
#pragma unroll
  for (int k = 0; k < 16; k += 4) {
    s0 += p[(size_t)(k + 0) * NSDIM * FDIM];
    s1 += p[(size_t)(k + 1) * NSDIM * FDIM];
    s2 += p[(size_t)(k + 2) * NSDIM * FDIM];
    s3 += p[(size_t)(k + 3) * NSDIM * FDIM];
  }
  part2[(size_t)g * NSDIM * FDIM + idx] = (s0 + s1) + (s2 + s3);
}

// ---------- hyper stage 2b ----------
__global__ __launch_bounds__(256) void hyper2b_k(const float* __restrict__ part2,
                                                 float* __restrict__ out1,
                                                 float* __restrict__ hyperT)
{
  const int idx = blockIdx.x * 256 + threadIdx.x;   // [0,4096)
  const float* __restrict__ p = part2 + idx;
  float s0 = 0.f, s1 = 0.f, s2 = 0.f, s3 = 0.f;
#pragma unroll
  for (int g = 0; g < HGRP; g += 4) {
    s0 += p[(size_t)(g + 0) * NSDIM * FDIM];
    s1 += p[(size_t)(g + 1) * NSDIM * FDIM];
    s2 += p[(size_t)(g + 2) * NSDIM * FDIM];
    s3 += p[(size_t)(g + 3) * NSDIM * FDIM];
  }
  const float s = (s0 + s1) + (s2 + s3);
  out1[idx] = s;
  const int j = idx >> 6, k = idx & 63;
  hyperT[k * NSDIM + j] = s;
}

__global__ void colhist_k(const float* __restrict__ H, int* __restrict__ hist, int nN)
{
  const int lane = threadIdx.x & 63;
  const int wid  = blockIdx.x * (blockDim.x >> 6) + (threadIdx.x >> 6);
  const int nw   = gridDim.x * (blockDim.x >> 6);
  int c0 = 0, c1 = 0, c2 = 0, c3 = 0, c4 = 0;
  for (int i = wid; i < nN; i += nw) {
    const int v = (int)H[(size_t)i * NSDIM + lane];
    c0 += (v == 0); c1 += (v == 1); c2 += (v == 2); c3 += (v == 3); c4 += (v == 4);
  }
  if (c0) atomicAdd(&hist[0 * NSDIM + lane], c0);
  if (c1) atomicAdd(&hist[1 * NSDIM + lane], c1);
  if (c2) atomicAdd(&hist[2 * NSDIM + lane], c2);
  if (c3) atomicAdd(&hist[3 * NSDIM + lane], c3);
  if (c4) atomicAdd(&hist[4 * NSDIM + lane], c4);
}

__global__ void colfin_k(const int* __restrict__ hist, float* __restrict__ cmax,
                         float* __restrict__ cden)
{
  const int j = threadIdx.x;
  if (j < NSDIM) {
    const int s0 = hist[j], s1 = hist[NSDIM + j], s2 = hist[2 * NSDIM + j];
    const int s3 = hist[3 * NSDIM + j], s4 = hist[4 * NSDIM + j];
    int m = 0;
    if (s1 > 0) m = 1;
    if (s2 > 0) m = 2;
    if (s3 > 0) m = 3;
    if (s4 > 0) m = 4;
    float den = 0.f;
    den += (float)s0 * expf((float)(0 - m));
    den += (float)s1 * expf((float)(1 - m));
    den += (float)s2 * expf((float)(2 - m));
    den += (float)s3 * expf((float)(3 - m));
    den += (float)s4 * expf((float)(4 - m));
    cmax[j] = (float)m;
    cden[j] = den;
  }
}

__global__ void hsoft_k(const float* __restrict__ H, const float* __restrict__ cmax,
                        const float* __restrict__ cden, float* __restrict__ out0, int nN)
{
  int idx = blockIdx.x * blockDim.x + threadIdx.x;
  int tot = nN * NSDIM;
  if (idx < tot) {
    int j = idx & (NSDIM - 1);
    out0[idx] = expf(H[idx] - cmax[j]) / cden[j];
  }
}

// ---------- host ----------
extern "C" void kernel_launch(void* const* d_in, const int* in_sizes, int n_in,
                              void* d_out, int out_size, void* d_ws, size_t ws_size,
                              hipStream_t stream)
{
  const int* edge_index = (const int*)d_in[0];
  const float* features = (const float*)d_in[1];
  const float* W_lin    = (const float*)d_in[2];
  const float* b_lin    = (const float*)d_in[3];
  const float* gcn0_W   = (const float*)d_in[4];
  const float* gcn0_b   = (const float*)d_in[5];
  const float* gcn1_W   = (const float*)d_in[6];
  const float* gcn1_b   = (const float*)d_in[7];
  const float* lin1_W   = (const float*)d_in[8];
  const float* lin1_b   = (const float*)d_in[9];

  const int E = in_sizes[0] / 2;
  const int N = in_sizes[1] / FDIM;

  const int* src = edge_index;
  const int* dst = edge_index + E;

  const int NB = (N + 255) >> 8;

  // workspace layout
  float* ws = (float*)d_ws;
  float* G  = ws;                                      // 3NF; aliased by ebuf + xws
  uint2* ebuf = (uint2*)G;                             // E pairs (8B) - G dead at use
  float* xws  = G;                                     // N*F scaled table (after csrD)

  int* ip = (int*)(G + (size_t)TREP * N * FDIM);
  int* bkcntS = ip; ip += 256;
  int* bkcntD = ip; ip += 256;
  int* bkoffS = ip; ip += 264;
  int* bkcurS = ip; ip += 256;
  int* bkoffD = ip; ip += 264;
  int* bkcurD = ip; ip += 256;
  int* cntS   = ip; ip += N;
  int* cntD   = ip; ip += N;
  int* cntR   = ip; ip += 3 * N;
  int* rowoffS = ip; ip += N + 64;
  int* rowoffD = ip; ip += N + 64;
  int* tilesum = ip; ip += (N + 255) / 256 + 8;
  int* tileoff = ip; ip += (N + 255) / 256 + 8;
  int* hist5   = ip; ip += 5 * NSDIM;
  float* dinv = (float*)ip; ip += 4 * N;
  unsigned* slots = (unsigned*)ip; ip += 2 * E;        // src CSR [0,E) | dst CSR [E,2E)
  float* xw0  = (float*)ip;
  float* bufA = xw0 + (size_t)N * FDIM;
  float* bufB = bufA + (size_t)4 * N * FDIM;
  float* Harr = bufB + (size_t)4 * N * FDIM;
  float* cmax  = Harr + (size_t)N * NSDIM;
  float* cden  = cmax + NSDIM;
  float* hyperT = cden + NSDIM;                        // NS*F
  float* hpart  = hyperT + NSDIM * FDIM;               // HPART * NS*F (8 MB)
  float* hpart2 = hpart + (size_t)HPART * NSDIM * FDIM; // HGRP * NS*F (512 KB)

  float* out0 = (float*)d_out;             // H_soft (N,NS)
  float* out1 = out0 + (size_t)N * NSDIM;  // hyper (NS,F)
  float* out2 = out1 + NSDIM * FDIM;       // dots (4N,NS)

  const int BLK = 256;
  const int WPB = BLK / 64;
  const int ntiles = (N + 255) / 256;
  auto wgrid = [](int items, int wpb) { return (items + wpb - 1) / wpb; };
  auto tgrid = [](int rows) { return (rows + 255) / 256; };
  const int ngrp = (N + 3) / 4;

  // zero: bucket counts, hist5, Harr
  hipMemsetAsync(bkcntS, 0, 512 * sizeof(int), stream);
  hipMemsetAsync(hist5, 0, (size_t)5 * NSDIM * sizeof(int), stream);
  hipMemsetAsync(Harr, 0, (size_t)N * NSDIM * sizeof(float), stream);

  // --- src-CSR (bucket-staged) ---
  bkhist2_k<<<256, BLK, 0, stream>>>(src, dst, bkcntS, bkcntD, E);
  bkscan2_k<<<1, 256, 0, stream>>>(bkcntS, bkcntD, bkoffS, bkcurS, bkoffD, bkcurD, NB);
  bkfillS_k<<<(E + 2047) / 2048, BLK, 0, stream>>>(src, dst, bkcurS, ebuf, E);
  cntfillS_k<<<NB, BLK, 0, stream>>>(ebuf, bkoffS, cntS, N);
  scanA_k<<<ntiles, 256, 0, stream>>>(cntS, rowoffS, tilesum, N);
  scanB_k<<<1, 256, 0, stream>>>(tilesum, tileoff, ntiles);
  scanC_k<<<ntiles, 256, 0, stream>>>(rowoffS, cntS, tileoff, N, ntiles);
  csrfill_k<<<NB, BLK, 0, stream>>>(ebuf, bkoffS, rowoffS, slots, N);

  // --- G + mask (ebuf dead; G overwrites it) ---
  {
    dim3 g(tgrid(N), TREP);
    gmat_k<<<g, BLK, 0, stream>>>(features, W_lin, b_lin, G, N);
  }
  mask_k<<<wgrid(ngrp, WPB), BLK, 0, stream>>>(rowoffS, slots, G, features, N);

  // --- dst-CSR (bucket-staged; ebuf overwrites dead G) ---
  bkfillD_k<<<NB, BLK, 0, stream>>>(rowoffS, slots, bkcurD, ebuf, N);
  cntfillD_k<<<NB, BLK, 0, stream>>>(ebuf, bkoffD, cntD, cntR, N);
  dinv_k<<<(4 * N + BLK - 1) / BLK, BLK, 0, stream>>>(cntD, cntR, dinv, N);
  scanA_k<<<ntiles, 256, 0, stream>>>(cntD, rowoffD, tilesum, N);
  scanB_k<<<1, 256, 0, stream>>>(tilesum, tileoff, ntiles);
  scanC_k<<<ntiles, 256, 0, stream>>>(rowoffD, cntD, tileoff, N, ntiles);
  csrfill_k<<<NB, BLK, 0, stream>>>(ebuf, bkoffD, rowoffD, slots + E, N);

  // --- GCN layers (xws overwrites dead ebuf) ---
  gemm_k<true><<<tgrid(N), BLK, 0, stream>>>(features, gcn0_W, xw0, N, xws, dinv, N);
  gather_finish_k<true, true><<<wgrid(ngrp, WPB), BLK, 0, stream>>>(
      rowoffD, slots + E, xws, xw0, dinv, gcn0_b, bufA, N);
  gemm_k<false><<<tgrid(4 * N), BLK, 0, stream>>>(bufA, gcn1_W, bufB, 4 * N, xws, dinv, N);
  gather_finish_k<false, false><<<wgrid(ngrp, WPB), BLK, 0, stream>>>(
      rowoffD, slots + E, xws, bufB, dinv, gcn1_b, bufA, N);

  // --- head ---
  logits_k<<<tgrid(4 * N), BLK, 0, stream>>>(bufA, lin1_W, lin1_b, Harr, 4 * N, N);
  hyper1_k<<<HPART, BLK, 0, stream>>>(Harr, bufA, hpart, N);
  {
    dim3 g2a(NSDIM * FDIM / 256, HGRP);
    hyper2a_k<<<g2a, 256, 0, stream>>>(hpart, hpart2);
  }
  hyper2b_k<<<NSDIM * FDIM / 256, 256, 0, stream>>>(hpart2, out1, hyperT);
  colhist_k<<<256, BLK, 0, stream>>>(Harr, hist5, N);
  colfin_k<<<1, 64, 0, stream>>>(hist5, cmax, cden);
  hsoft_k<<<(N * NSDIM + BLK - 1) / BLK, BLK, 0, stream>>>(Harr, cmax, cden, out0, N);
  dots_k<<<tgrid(N), BLK, 0, stream>>>(features, hyperT, out2, N);
}